// Round 1
// baseline (347.012 us; speedup 1.0000x reference)
//
#include <hip/hip_runtime.h>

#define LOG2E 1.4426950408889634f

typedef _Float16 f16x8_t __attribute__((ext_vector_type(8)));
typedef _Float16 f16x4_t __attribute__((ext_vector_type(4)));
typedef float    f32x4_t __attribute__((ext_vector_type(4)));

// async 16B/lane global->LDS copy. LDS dest is wave-uniform base + lane*16.
__device__ __forceinline__ void async_copy16(void* lds, const void* g) {
    __builtin_amdgcn_global_load_lds(
        (const __attribute__((address_space(1))) unsigned char*)g,
        (__attribute__((address_space(3))) unsigned char*)lds, 16, 0, 0);
}

// ---------------- cast fp32 -> fp16 (vectorized x4) ----------------
__global__ void cast_f32_f16_k(const float* __restrict__ in, _Float16* __restrict__ out, int n4) {
    int i = blockIdx.x * blockDim.x + threadIdx.x;
    if (i >= n4) return;
    float4 v = ((const float4*)in)[i];
    f16x4_t o = { (_Float16)v.x, (_Float16)v.y, (_Float16)v.z, (_Float16)v.w };
    ((f16x4_t*)out)[i] = o;
}

// ---------------- transpose + cast: in [R][C] fp32 -> out [C][R] fp16 ----------------
__global__ void transpose_cast_k(const float* __restrict__ in, _Float16* __restrict__ out,
                                 int R, int C) {
    __shared__ _Float16 tl[64][65];
    const int t = threadIdx.x;
    const int c = t & 63;
    const int r4 = t >> 6;
    const int r0 = blockIdx.y * 64, c0 = blockIdx.x * 64;
#pragma unroll
    for (int i = 0; i < 16; ++i) {
        int r = r4 + i * 4;
        tl[c][r] = (_Float16)in[(size_t)(r0 + r) * C + c0 + c];
    }
    __syncthreads();
#pragma unroll
    for (int i = 0; i < 16; ++i) {
        int rr = r4 + i * 4;
        out[(size_t)(c0 + rr) * R + r0 + c] = tl[rr][c];
    }
}

// ---------------- GEMM: C[M][N] = A[M][K] * BT[N][K]^T (+bias), fp16 in, fp32 out ----------------
// m97 structure: 128x128 tile, BK=32, 4 waves (2x2), 4x4 MFMA tiles/wave, global_load_lds x16.
template <bool BIAS>
__global__ __launch_bounds__(256, 2)
void gemm_f16_k(const _Float16* __restrict__ A, const _Float16* __restrict__ BT,
                float* __restrict__ C, const float* __restrict__ bias,
                int M, int N, int K) {
    __shared__ _Float16 As[128 * 32];
    __shared__ _Float16 Bs[128 * 32];
    const int tid = threadIdx.x;
    const int wid = tid >> 6, lane = tid & 63;
    const int qd = lane >> 4, ln = lane & 15;
    const int m0 = blockIdx.x * 128, n0 = blockIdx.y * 128;
    const int wm = (wid >> 1) * 64, wn = (wid & 1) * 64;

    f32x4_t acc[4][4] = {};

    const int srow = lane >> 2;        // 0..15 within a 16-row segment
    const int skk  = (lane & 3) * 8;   // k offset in halfs

    for (int k0 = 0; k0 < K; k0 += 32) {
        __syncthreads();
#pragma unroll
        for (int p = 0; p < 2; ++p) {
            const int seg = p * 4 + wid;           // 0..7, 1KB per wave-pass
            const int row = seg * 16 + srow;       // 0..127
            async_copy16(As + seg * 512, A  + (size_t)(m0 + row) * K + k0 + skk);
            async_copy16(Bs + seg * 512, BT + (size_t)(n0 + row) * K + k0 + skk);
        }
        __syncthreads();
        f16x8_t a[4], b[4];
#pragma unroll
        for (int i = 0; i < 4; ++i)
            a[i] = *(const f16x8_t*)&As[(wm + i * 16 + ln) * 32 + qd * 8];
#pragma unroll
        for (int j = 0; j < 4; ++j)
            b[j] = *(const f16x8_t*)&Bs[(wn + j * 16 + ln) * 32 + qd * 8];
#pragma unroll
        for (int i = 0; i < 4; ++i)
#pragma unroll
            for (int j = 0; j < 4; ++j)
                acc[i][j] = __builtin_amdgcn_mfma_f32_16x16x32_f16(a[i], b[j], acc[i][j], 0, 0, 0);
    }
#pragma unroll
    for (int i = 0; i < 4; ++i)
#pragma unroll
        for (int j = 0; j < 4; ++j) {
            const int col = n0 + wn + j * 16 + ln;
            const float bv = BIAS ? bias[col] : 0.0f;
#pragma unroll
            for (int r = 0; r < 4; ++r) {
                const int row = m0 + wm + i * 16 + qd * 4 + r;
                C[(size_t)row * N + col] = acc[i][j][r] + bv;
            }
        }
}

// ---------------- per-head LayerNorm on q,k; cast v; repack to [b,h,n,d] fp16 ----------------
// Q gets * sqrt(64) * log2(e) folded in so attention can use exp2.
__global__ void ln_qkv_k(const float* __restrict__ qkv, const float* __restrict__ ln_w,
                         const float* __restrict__ ln_b, _Float16* __restrict__ Qb,
                         _Float16* __restrict__ Kb, _Float16* __restrict__ Vb) {
    const int tid = threadIdx.x;
    const int wid = tid >> 6, lane = tid & 63;
    const int row = blockIdx.x * 4 + wid;   // 0..65535 = (token, head)
    const int t = row >> 4;                 // token 0..4095
    const int h = row & 15;
    const int b = t >> 11, n = t & 2047;
    const size_t base = (size_t)t * 3072 + h * 64 + lane;
    float q = qkv[base];
    float k = qkv[base + 1024];
    float v = qkv[base + 2048];
    const float wv = ln_w[lane], bv = ln_b[lane];

    float sq = q, sk = k;
#pragma unroll
    for (int m = 1; m < 64; m <<= 1) { sq += __shfl_xor(sq, m); sk += __shfl_xor(sk, m); }
    sq *= (1.0f / 64.0f); sk *= (1.0f / 64.0f);
    const float dq = q - sq, dk = k - sk;
    float vq = dq * dq, vk = dk * dk;
#pragma unroll
    for (int m = 1; m < 64; m <<= 1) { vq += __shfl_xor(vq, m); vk += __shfl_xor(vk, m); }
    vq *= (1.0f / 64.0f); vk *= (1.0f / 64.0f);
    const float yq = dq * rsqrtf(vq + 1e-5f) * wv + bv;
    const float yk = dk * rsqrtf(vk + 1e-5f) * wv + bv;
    const size_t obase = ((size_t)((b * 16 + h) * 2048 + n)) * 64 + lane;
    Qb[obase] = (_Float16)(yq * (8.0f * LOG2E));
    Kb[obase] = (_Float16)yk;
    Vb[obase] = (_Float16)v;
}

// ---------------- flash-style causal attention ----------------
// grid: (B*H, N/256). Block = 4 waves; wave w owns q rows [q0+w*64, +64).
// KV step = 64. K staged via global_load_lds into split layout Ks[2][64][32]
// (keeps ds_read rows at 32-half stride -> conflict-free). V transposed into
// VT[64][72] (stride 72 halfs = 16B aligned). P round-trips through Pl[w][64][72].
__global__ __launch_bounds__(256, 1)
void attn_k(const _Float16* __restrict__ Q, const _Float16* __restrict__ K,
            const _Float16* __restrict__ V, _Float16* __restrict__ O) {
    __shared__ _Float16 Ks[2][64][32];
    __shared__ _Float16 VT[64][72];
    __shared__ _Float16 Pl[4][64][72];

    const int tid = threadIdx.x;
    const int wid = tid >> 6, lane = tid & 63;
    const int qd = lane >> 4, ln = lane & 15;
    const int bh = blockIdx.x;
    const int q0 = blockIdx.y * 256;
    const int b = bh >> 4, h = bh & 15;
    const size_t kvbase = (size_t)bh * 2048 * 64;
    const int qrow0 = q0 + wid * 64;

    // Q fragments live in registers for the whole kernel (A-operand layout).
    f16x8_t qf[4][2];
#pragma unroll
    for (int i = 0; i < 4; ++i)
#pragma unroll
        for (int s = 0; s < 2; ++s)
            qf[i][s] = *(const f16x8_t*)&Q[kvbase + (size_t)(qrow0 + i * 16 + ln) * 64 + s * 32 + qd * 8];

    f32x4_t o[4][4] = {};
    float mr[4][4], lr[4][4];
#pragma unroll
    for (int i = 0; i < 4; ++i)
#pragma unroll
        for (int r = 0; r < 4; ++r) { mr[i][r] = -3.0e38f; lr[i][r] = 0.0f; }

    const int nsteps  = q0 / 64 + 4;            // staged by everyone
    const int mysteps = q0 / 64 + wid + 1;      // computed by this wave

    for (int st = 0; st < nsteps; ++st) {
        const int kv0 = st * 64;
        __syncthreads();
        // stage K (async, 2 passes/wave)
#pragma unroll
        for (int p = 0; p < 2; ++p) {
            const int seg = p * 4 + wid;        // 0..7
            const int oh = seg * 512;           // uniform half index of segment base
            const int hidx = oh + lane * 8;     // this lane's half index
            const int s_ = hidx >> 11;
            const int rrow = (hidx >> 5) & 63;
            const int kk = hidx & 31;
            async_copy16((_Float16*)Ks + oh,
                         K + kvbase + (size_t)(kv0 + rrow) * 64 + s_ * 32 + kk);
        }
        // stage V transposed: lane l reads 16B column slab (L2-resident), LDS writes conflict-free
#pragma unroll
        for (int e = 0; e < 2; ++e) {
            const int idx = tid + e * 256;      // 0..511
            const int kv = idx & 63;
            const int d0 = (idx >> 6) * 8;      // 0..56
            f16x8_t vv = *(const f16x8_t*)&V[kvbase + (size_t)(kv0 + kv) * 64 + d0];
#pragma unroll
            for (int j = 0; j < 8; ++j) VT[d0 + j][kv] = vv[j];
        }
        __syncthreads();
        if (st >= mysteps) continue;   // fully above diagonal for this wave (barriers stay uniform)

        // S = Q K^T  (64x64 per wave)
        f16x8_t kb[4][2];
#pragma unroll
        for (int j = 0; j < 4; ++j)
#pragma unroll
            for (int s = 0; s < 2; ++s)
                kb[j][s] = *(const f16x8_t*)&Ks[s][j * 16 + ln][qd * 8];
        f32x4_t sc[4][4];
#pragma unroll
        for (int i = 0; i < 4; ++i)
#pragma unroll
            for (int j = 0; j < 4; ++j) {
                f32x4_t s0 = {};
                s0 = __builtin_amdgcn_mfma_f32_16x16x32_f16(qf[i][0], kb[j][0], s0, 0, 0, 0);
                s0 = __builtin_amdgcn_mfma_f32_16x16x32_f16(qf[i][1], kb[j][1], s0, 0, 0, 0);
                sc[i][j] = s0;
            }
        // causal mask (only the diagonal step needs it)
        if (st == mysteps - 1) {
#pragma unroll
            for (int i = 0; i < 4; ++i)
#pragma unroll
                for (int j = 0; j < 4; ++j)
#pragma unroll
                    for (int r = 0; r < 4; ++r) {
                        const int kv = kv0 + j * 16 + ln;
                        const int qr = qrow0 + i * 16 + qd * 4 + r;
                        if (kv > qr) sc[i][j][r] = -3.0e38f;
                    }
        }
        // online softmax (fp32, log2 domain), write P to LDS as fp16
#pragma unroll
        for (int i = 0; i < 4; ++i) {
#pragma unroll
            for (int r = 0; r < 4; ++r) {
                float mx = fmaxf(fmaxf(sc[i][0][r], sc[i][1][r]), fmaxf(sc[i][2][r], sc[i][3][r]));
                mx = fmaxf(mx, __shfl_xor(mx, 1));
                mx = fmaxf(mx, __shfl_xor(mx, 2));
                mx = fmaxf(mx, __shfl_xor(mx, 4));
                mx = fmaxf(mx, __shfl_xor(mx, 8));
                const float mn = fmaxf(mr[i][r], mx);
                const float al = exp2f(mr[i][r] - mn);
                mr[i][r] = mn;
                float rs = 0.0f;
#pragma unroll
                for (int j = 0; j < 4; ++j) {
                    const float p = exp2f(sc[i][j][r] - mn);
                    sc[i][j][r] = p;
                    rs += p;
                }
                rs += __shfl_xor(rs, 1);
                rs += __shfl_xor(rs, 2);
                rs += __shfl_xor(rs, 4);
                rs += __shfl_xor(rs, 8);
                lr[i][r] = lr[i][r] * al + rs;
                const int prow = i * 16 + qd * 4 + r;
#pragma unroll
                for (int j = 0; j < 4; ++j)
                    Pl[wid][prow][j * 16 + ln] = (_Float16)sc[i][j][r];
#pragma unroll
                for (int dt = 0; dt < 4; ++dt) o[i][dt][r] *= al;
            }
        }
        // make P writes visible to this wave's reads
        asm volatile("s_waitcnt lgkmcnt(0)" ::: "memory");
        // O += P V
        f16x8_t vf[4][2];
#pragma unroll
        for (int dt = 0; dt < 4; ++dt)
#pragma unroll
            for (int s = 0; s < 2; ++s)
                vf[dt][s] = *(const f16x8_t*)&VT[dt * 16 + ln][s * 32 + qd * 8];
#pragma unroll
        for (int i = 0; i < 4; ++i) {
            f16x8_t p0 = *(const f16x8_t*)&Pl[wid][i * 16 + ln][qd * 8];
            f16x8_t p1 = *(const f16x8_t*)&Pl[wid][i * 16 + ln][32 + qd * 8];
#pragma unroll
            for (int dt = 0; dt < 4; ++dt) {
                o[i][dt] = __builtin_amdgcn_mfma_f32_16x16x32_f16(p0, vf[dt][0], o[i][dt], 0, 0, 0);
                o[i][dt] = __builtin_amdgcn_mfma_f32_16x16x32_f16(p1, vf[dt][1], o[i][dt], 0, 0, 0);
            }
        }
    }
    // epilogue: O/l, store fp16 to [b, n, h*64+d]
#pragma unroll
    for (int i = 0; i < 4; ++i)
#pragma unroll
        for (int r = 0; r < 4; ++r) {
            const float inv = 1.0f / lr[i][r];
            const int qr = qrow0 + i * 16 + qd * 4 + r;
#pragma unroll
            for (int dt = 0; dt < 4; ++dt)
                O[((size_t)(b * 2048 + qr)) * 1024 + h * 64 + dt * 16 + ln] =
                    (_Float16)(o[i][dt][r] * inv);
        }
}

extern "C" void kernel_launch(void* const* d_in, const int* in_sizes, int n_in,
                              void* d_out, int out_size, void* d_ws, size_t ws_size,
                              hipStream_t stream) {
    const float* x      = (const float*)d_in[0];
    const float* w_qkv  = (const float*)d_in[1];
    const float* w_proj = (const float*)d_in[2];
    const float* b_proj = (const float*)d_in[3];
    const float* ln_w   = (const float*)d_in[4];
    const float* ln_b   = (const float*)d_in[5];
    float* out = (float*)d_out;

    // workspace partition (96 MB total)
    char* w = (char*)d_ws;
    float*     qkv    = (float*)w;     w += (size_t)4096 * 3072 * 4;  // 48 MB
    _Float16*  xh     = (_Float16*)w;  w += (size_t)4096 * 1024 * 2;  // 8 MB
    _Float16*  wqkvT  = (_Float16*)w;  w += (size_t)3072 * 1024 * 2;  // 6 MB
    _Float16*  wprojT = (_Float16*)w;  w += (size_t)1024 * 1024 * 2;  // 2 MB
    _Float16*  Qb     = (_Float16*)w;  w += (size_t)32 * 2048 * 64 * 2; // 8 MB
    _Float16*  Kb     = (_Float16*)w;  w += (size_t)32 * 2048 * 64 * 2; // 8 MB
    _Float16*  Vb     = (_Float16*)w;  w += (size_t)32 * 2048 * 64 * 2; // 8 MB
    _Float16*  Ah     = (_Float16*)w;  w += (size_t)4096 * 1024 * 2;  // 8 MB

    cast_f32_f16_k<<<4096, 256, 0, stream>>>(x, xh, 4096 * 1024 / 4);
    transpose_cast_k<<<dim3(48, 16), 256, 0, stream>>>(w_qkv, wqkvT, 1024, 3072);
    transpose_cast_k<<<dim3(16, 16), 256, 0, stream>>>(w_proj, wprojT, 1024, 1024);
    gemm_f16_k<false><<<dim3(32, 24), 256, 0, stream>>>(xh, wqkvT, qkv, nullptr, 4096, 3072, 1024);
    ln_qkv_k<<<16384, 256, 0, stream>>>(qkv, ln_w, ln_b, Qb, Kb, Vb);
    attn_k<<<dim3(32, 8), 256, 0, stream>>>(Qb, Kb, Vb, Ah);
    gemm_f16_k<true><<<dim3(32, 8), 256, 0, stream>>>(Ah, wprojT, out, b_proj, 4096, 1024, 1024);
}

// Round 2
// 220.294 us; speedup vs baseline: 1.5752x; 1.5752x over previous
//
#include <hip/hip_runtime.h>

#define LOG2E 1.4426950408889634f

typedef _Float16 f16x8_t __attribute__((ext_vector_type(8)));
typedef _Float16 f16x4_t __attribute__((ext_vector_type(4)));
typedef float    f32x4_t __attribute__((ext_vector_type(4)));

// async 16B/lane global->LDS copy. LDS dest is wave-uniform base + lane*16.
__device__ __forceinline__ void async_copy16(void* lds, const void* g) {
    __builtin_amdgcn_global_load_lds(
        (const __attribute__((address_space(1))) unsigned char*)g,
        (__attribute__((address_space(3))) unsigned char*)lds, 16, 0, 0);
}

// ---------------- cast fp32 -> fp16 (vectorized x4) ----------------
__global__ void cast_f32_f16_k(const float* __restrict__ in, _Float16* __restrict__ out, int n4) {
    int i = blockIdx.x * blockDim.x + threadIdx.x;
    if (i >= n4) return;
    float4 v = ((const float4*)in)[i];
    f16x4_t o = { (_Float16)v.x, (_Float16)v.y, (_Float16)v.z, (_Float16)v.w };
    ((f16x4_t*)out)[i] = o;
}

// ---------------- transpose + cast: in [R][C] fp32 -> out [C][R] fp16 ----------------
__global__ void transpose_cast_k(const float* __restrict__ in, _Float16* __restrict__ out,
                                 int R, int C) {
    __shared__ _Float16 tl[64][65];
    const int t = threadIdx.x;
    const int c = t & 63;
    const int r4 = t >> 6;
    const int r0 = blockIdx.y * 64, c0 = blockIdx.x * 64;
#pragma unroll
    for (int i = 0; i < 16; ++i) {
        int r = r4 + i * 4;
        tl[c][r] = (_Float16)in[(size_t)(r0 + r) * C + c0 + c];
    }
    __syncthreads();
#pragma unroll
    for (int i = 0; i < 16; ++i) {
        int rr = r4 + i * 4;
        out[(size_t)(c0 + rr) * R + r0 + c] = tl[rr][c];
    }
}

// ---------------- GEMM: C[M][N] = A[M][K] * BT[N][K]^T (+bias), fp16 in ----------------
// 128x128 tile, BK=64 staged as two 32-half planes (dense, conflict-free b128 reads),
// 4 waves (2x2), 4x4 MFMA tiles/wave, global_load_lds width=16.
template <typename OutT, bool BIAS>
__global__ __launch_bounds__(256, 2)
void gemm_f16_k(const _Float16* __restrict__ A, const _Float16* __restrict__ BT,
                OutT* __restrict__ C, const float* __restrict__ bias,
                int M, int N, int K) {
    __shared__ _Float16 As[2][128][32];
    __shared__ _Float16 Bs[2][128][32];
    const int tid = threadIdx.x;
    const int wid = tid >> 6, lane = tid & 63;
    const int qd = lane >> 4, ln = lane & 15;
    const int m0 = blockIdx.x * 128, n0 = blockIdx.y * 128;
    const int wm = (wid >> 1) * 64, wn = (wid & 1) * 64;

    f32x4_t acc[4][4] = {};

    const int srow = lane >> 2;        // 0..15 within a 16-row segment
    const int skk  = (lane & 3) * 8;   // k offset in halfs within a plane

    for (int k0 = 0; k0 < K; k0 += 64) {
        __syncthreads();
#pragma unroll
        for (int p = 0; p < 4; ++p) {
            const int seg = p * 4 + wid;           // 0..15
            const int s   = seg >> 3;              // plane
            const int rg  = seg & 7;               // row group
            const int row = rg * 16 + srow;        // 0..127
            const size_t goff = (size_t)row * K + k0 + s * 32 + skk;
            async_copy16(&As[0][0][0] + seg * 512, A  + (size_t)m0 * K + goff);
            async_copy16(&Bs[0][0][0] + seg * 512, BT + (size_t)n0 * K + goff);
        }
        __syncthreads();
#pragma unroll
        for (int s = 0; s < 2; ++s) {
            f16x8_t a[4], b[4];
#pragma unroll
            for (int i = 0; i < 4; ++i)
                a[i] = *(const f16x8_t*)&As[s][wm + i * 16 + ln][qd * 8];
#pragma unroll
            for (int j = 0; j < 4; ++j)
                b[j] = *(const f16x8_t*)&Bs[s][wn + j * 16 + ln][qd * 8];
#pragma unroll
            for (int i = 0; i < 4; ++i)
#pragma unroll
                for (int j = 0; j < 4; ++j)
                    acc[i][j] = __builtin_amdgcn_mfma_f32_16x16x32_f16(a[i], b[j], acc[i][j], 0, 0, 0);
        }
    }
#pragma unroll
    for (int i = 0; i < 4; ++i)
#pragma unroll
        for (int j = 0; j < 4; ++j) {
            const int col = n0 + wn + j * 16 + ln;
            const float bv = BIAS ? bias[col] : 0.0f;
#pragma unroll
            for (int r = 0; r < 4; ++r) {
                const int row = m0 + wm + i * 16 + qd * 4 + r;
                C[(size_t)row * N + col] = (OutT)(acc[i][j][r] + bv);
            }
        }
}

// ---------------- per-head LayerNorm on q,k; cast v; repack to [b,h,n,d] fp16 ----------------
// Q gets * sqrt(64) * log2(e) folded in so attention can use exp2.
__global__ void ln_qkv_k(const _Float16* __restrict__ qkv, const float* __restrict__ ln_w,
                         const float* __restrict__ ln_b, _Float16* __restrict__ Qb,
                         _Float16* __restrict__ Kb, _Float16* __restrict__ Vb) {
    const int tid = threadIdx.x;
    const int wid = tid >> 6, lane = tid & 63;
    const int row = blockIdx.x * 4 + wid;   // 0..65535 = (token, head)
    const int t = row >> 4;                 // token 0..4095
    const int h = row & 15;
    const int b = t >> 11, n = t & 2047;
    const size_t base = (size_t)t * 3072 + h * 64 + lane;
    float q = (float)qkv[base];
    float k = (float)qkv[base + 1024];
    float v = (float)qkv[base + 2048];
    const float wv = ln_w[lane], bv = ln_b[lane];

    float sq = q, sk = k;
#pragma unroll
    for (int m = 1; m < 64; m <<= 1) { sq += __shfl_xor(sq, m); sk += __shfl_xor(sk, m); }
    sq *= (1.0f / 64.0f); sk *= (1.0f / 64.0f);
    const float dq = q - sq, dk = k - sk;
    float vq = dq * dq, vk = dk * dk;
#pragma unroll
    for (int m = 1; m < 64; m <<= 1) { vq += __shfl_xor(vq, m); vk += __shfl_xor(vk, m); }
    vq *= (1.0f / 64.0f); vk *= (1.0f / 64.0f);
    const float yq = dq * rsqrtf(vq + 1e-5f) * wv + bv;
    const float yk = dk * rsqrtf(vk + 1e-5f) * wv + bv;
    const size_t obase = ((size_t)((b * 16 + h) * 2048 + n)) * 64 + lane;
    Qb[obase] = (_Float16)(yq * (8.0f * LOG2E));
    Kb[obase] = (_Float16)yk;
    Vb[obase] = (_Float16)v;
}

// ---------------- flash-style causal attention, balanced small blocks ----------------
// grid: (B*H, 32 bands reversed — biggest first). Block = 4 waves; wave w owns q rows
// [band*64 + w*16, +16). Every wave computes every KV step (in-block balanced).
// KV step = 64. K staged async into split Ks[2][64][32] (dense b128 reads).
// V register-transposed into VT[64][72]. P per-wave in Pl[w][16][72].
// Row-sum of P computed by MFMA against a constant all-ones B operand.
__global__ __launch_bounds__(256, 2)
void attn_k(const _Float16* __restrict__ Q, const _Float16* __restrict__ K,
            const _Float16* __restrict__ V, _Float16* __restrict__ O) {
    __shared__ _Float16 Ks[2][64][32];
    __shared__ _Float16 VT[64][72];
    __shared__ _Float16 Pl[4][16][72];

    const int tid = threadIdx.x;
    const int wid = tid >> 6, lane = tid & 63;
    const int qd = lane >> 4, ln = lane & 15;
    const int bh = blockIdx.x;
    const int band = 31 - blockIdx.y;       // biggest bands dispatch first
    const int b = bh >> 4, h = bh & 15;
    const size_t kvbase = (size_t)bh * 2048 * 64;
    const int qrow0 = band * 64 + wid * 16; // this wave's 16 q rows

    // Q fragments live in registers for the whole kernel (A-operand layout).
    f16x8_t qf[2];
#pragma unroll
    for (int s = 0; s < 2; ++s)
        qf[s] = *(const f16x8_t*)&Q[kvbase + (size_t)(qrow0 + ln) * 64 + s * 32 + qd * 8];

    const f16x8_t ones = { (_Float16)1.f, (_Float16)1.f, (_Float16)1.f, (_Float16)1.f,
                           (_Float16)1.f, (_Float16)1.f, (_Float16)1.f, (_Float16)1.f };

    f32x4_t o[4] = {};
    f32x4_t ol = {};                        // row-sum accumulator (via ones MFMA)
    float mr[4] = { -3.0e38f, -3.0e38f, -3.0e38f, -3.0e38f };

    const int nsteps = band + 1;

    for (int st = 0; st < nsteps; ++st) {
        const int kv0 = st * 64;
        __syncthreads();
        // stage K (async, 2 passes/wave) into split planes
#pragma unroll
        for (int p = 0; p < 2; ++p) {
            const int seg = p * 4 + wid;        // 0..7
            const int oh = seg * 512;           // uniform half index of segment base
            const int hidx = oh + lane * 8;     // this lane's half index
            const int s_ = hidx >> 11;
            const int rrow = (hidx >> 5) & 63;
            const int kk = hidx & 31;
            async_copy16((_Float16*)Ks + oh,
                         K + kvbase + (size_t)(kv0 + rrow) * 64 + s_ * 32 + kk);
        }
        // stage V transposed (register transpose, coalesced global f16x8 reads)
#pragma unroll
        for (int e = 0; e < 2; ++e) {
            const int idx = tid + e * 256;      // 0..511
            const int kv = idx & 63;
            const int d0 = (idx >> 6) * 8;      // 0..56
            f16x8_t vv = *(const f16x8_t*)&V[kvbase + (size_t)(kv0 + kv) * 64 + d0];
#pragma unroll
            for (int j = 0; j < 8; ++j) VT[d0 + j][kv] = vv[j];
        }
        __syncthreads();

        // S = Q K^T  (16x64 per wave)
        f32x4_t sc[4];
#pragma unroll
        for (int j = 0; j < 4; ++j) {
            f16x8_t kb0 = *(const f16x8_t*)&Ks[0][j * 16 + ln][qd * 8];
            f16x8_t kb1 = *(const f16x8_t*)&Ks[1][j * 16 + ln][qd * 8];
            f32x4_t s0 = {};
            s0 = __builtin_amdgcn_mfma_f32_16x16x32_f16(qf[0], kb0, s0, 0, 0, 0);
            s0 = __builtin_amdgcn_mfma_f32_16x16x32_f16(qf[1], kb1, s0, 0, 0, 0);
            sc[j] = s0;
        }
        // causal mask (only the diagonal step needs it)
        if (st == nsteps - 1) {
#pragma unroll
            for (int j = 0; j < 4; ++j) {
                const int kv = kv0 + j * 16 + ln;
#pragma unroll
                for (int r = 0; r < 4; ++r) {
                    const int qr = qrow0 + qd * 4 + r;
                    if (kv > qr) sc[j][r] = -3.0e38f;
                }
            }
        }
        // online softmax (fp32, log2 domain), write P to LDS as fp16
#pragma unroll
        for (int r = 0; r < 4; ++r) {
            float mx = fmaxf(fmaxf(sc[0][r], sc[1][r]), fmaxf(sc[2][r], sc[3][r]));
            mx = fmaxf(mx, __shfl_xor(mx, 1));
            mx = fmaxf(mx, __shfl_xor(mx, 2));
            mx = fmaxf(mx, __shfl_xor(mx, 4));
            mx = fmaxf(mx, __shfl_xor(mx, 8));
            const float mn = fmaxf(mr[r], mx);
            const float al = exp2f(mr[r] - mn);
            mr[r] = mn;
            const int prow = qd * 4 + r;
#pragma unroll
            for (int j = 0; j < 4; ++j) {
                const float p = exp2f(sc[j][r] - mn);
                Pl[wid][prow][j * 16 + ln] = (_Float16)p;
            }
#pragma unroll
            for (int dt = 0; dt < 4; ++dt) o[dt][r] *= al;
            ol[r] *= al;
        }
        // make P writes visible to this wave's reads
        asm volatile("s_waitcnt lgkmcnt(0)" ::: "memory");
        // O += P V ; ol += P * ones (row sums)
        f16x8_t p0 = *(const f16x8_t*)&Pl[wid][ln][qd * 8];
        f16x8_t p1 = *(const f16x8_t*)&Pl[wid][ln][32 + qd * 8];
#pragma unroll
        for (int dt = 0; dt < 4; ++dt) {
            f16x8_t v0 = *(const f16x8_t*)&VT[dt * 16 + ln][qd * 8];
            f16x8_t v1 = *(const f16x8_t*)&VT[dt * 16 + ln][32 + qd * 8];
            o[dt] = __builtin_amdgcn_mfma_f32_16x16x32_f16(p0, v0, o[dt], 0, 0, 0);
            o[dt] = __builtin_amdgcn_mfma_f32_16x16x32_f16(p1, v1, o[dt], 0, 0, 0);
        }
        ol = __builtin_amdgcn_mfma_f32_16x16x32_f16(p0, ones, ol, 0, 0, 0);
        ol = __builtin_amdgcn_mfma_f32_16x16x32_f16(p1, ones, ol, 0, 0, 0);
    }
    // epilogue: O/l, store fp16 to [b, n, h*64+d]
#pragma unroll
    for (int r = 0; r < 4; ++r) {
        const float inv = 1.0f / ol[r];
        const int qr = qrow0 + qd * 4 + r;
#pragma unroll
        for (int dt = 0; dt < 4; ++dt)
            O[((size_t)(b * 2048 + qr)) * 1024 + h * 64 + dt * 16 + ln] =
                (_Float16)(o[dt][r] * inv);
    }
}

extern "C" void kernel_launch(void* const* d_in, const int* in_sizes, int n_in,
                              void* d_out, int out_size, void* d_ws, size_t ws_size,
                              hipStream_t stream) {
    const float* x      = (const float*)d_in[0];
    const float* w_qkv  = (const float*)d_in[1];
    const float* w_proj = (const float*)d_in[2];
    const float* b_proj = (const float*)d_in[3];
    const float* ln_w   = (const float*)d_in[4];
    const float* ln_b   = (const float*)d_in[5];
    float* out = (float*)d_out;

    // workspace partition
    char* w = (char*)d_ws;
    _Float16*  qkv    = (_Float16*)w;  w += (size_t)4096 * 3072 * 2;  // 24 MB
    _Float16*  xh     = (_Float16*)w;  w += (size_t)4096 * 1024 * 2;  // 8 MB
    _Float16*  wqkvT  = (_Float16*)w;  w += (size_t)3072 * 1024 * 2;  // 6 MB
    _Float16*  wprojT = (_Float16*)w;  w += (size_t)1024 * 1024 * 2;  // 2 MB
    _Float16*  Qb     = (_Float16*)w;  w += (size_t)32 * 2048 * 64 * 2; // 8 MB
    _Float16*  Kb     = (_Float16*)w;  w += (size_t)32 * 2048 * 64 * 2; // 8 MB
    _Float16*  Vb     = (_Float16*)w;  w += (size_t)32 * 2048 * 64 * 2; // 8 MB
    _Float16*  Ah     = (_Float16*)w;  w += (size_t)4096 * 1024 * 2;  // 8 MB

    cast_f32_f16_k<<<4096, 256, 0, stream>>>(x, xh, 4096 * 1024 / 4);
    transpose_cast_k<<<dim3(48, 16), 256, 0, stream>>>(w_qkv, wqkvT, 1024, 3072);
    transpose_cast_k<<<dim3(16, 16), 256, 0, stream>>>(w_proj, wprojT, 1024, 1024);
    gemm_f16_k<_Float16, false><<<dim3(32, 24), 256, 0, stream>>>(xh, wqkvT, qkv, nullptr, 4096, 3072, 1024);
    ln_qkv_k<<<16384, 256, 0, stream>>>(qkv, ln_w, ln_b, Qb, Kb, Vb);
    attn_k<<<dim3(32, 32), 256, 0, stream>>>(Qb, Kb, Vb, Ah);
    gemm_f16_k<float, true><<<dim3(32, 8), 256, 0, stream>>>(Ah, wprojT, out, b_proj, 4096, 1024, 1024);
}

// Round 3
// 211.831 us; speedup vs baseline: 1.6382x; 1.0400x over previous
//
#include <hip/hip_runtime.h>

#define LOG2E 1.4426950408889634f

typedef _Float16 f16x8_t __attribute__((ext_vector_type(8)));
typedef _Float16 f16x4_t __attribute__((ext_vector_type(4)));
typedef float    f32x4_t __attribute__((ext_vector_type(4)));

#define MFMA32(a, b, c) __builtin_amdgcn_mfma_f32_16x16x32_f16(a, b, c, 0, 0, 0)
#define MFMA16(a, b, c) __builtin_amdgcn_mfma_f32_16x16x16f16(a, b, c, 0, 0, 0)

// async 16B/lane global->LDS copy. LDS dest is wave-uniform base + lane*16.
__device__ __forceinline__ void async_copy16(void* lds, const void* g) {
    __builtin_amdgcn_global_load_lds(
        (const __attribute__((address_space(1))) unsigned char*)g,
        (__attribute__((address_space(3))) unsigned char*)lds, 16, 0, 0);
}

// ---------------- cast fp32 -> fp16 (vectorized x4) ----------------
__global__ void cast_f32_f16_k(const float* __restrict__ in, _Float16* __restrict__ out, int n4) {
    int i = blockIdx.x * blockDim.x + threadIdx.x;
    if (i >= n4) return;
    float4 v = ((const float4*)in)[i];
    f16x4_t o = { (_Float16)v.x, (_Float16)v.y, (_Float16)v.z, (_Float16)v.w };
    ((f16x4_t*)out)[i] = o;
}

// ---------------- transpose + cast: in [R][C] fp32 -> out [C][R] fp16 ----------------
__global__ void transpose_cast_k(const float* __restrict__ in, _Float16* __restrict__ out,
                                 int R, int C) {
    __shared__ _Float16 tl[64][65];
    const int t = threadIdx.x;
    const int c = t & 63;
    const int r4 = t >> 6;
    const int r0 = blockIdx.y * 64, c0 = blockIdx.x * 64;
#pragma unroll
    for (int i = 0; i < 16; ++i) {
        int r = r4 + i * 4;
        tl[c][r] = (_Float16)in[(size_t)(r0 + r) * C + c0 + c];
    }
    __syncthreads();
#pragma unroll
    for (int i = 0; i < 16; ++i) {
        int rr = r4 + i * 4;
        out[(size_t)(c0 + rr) * R + r0 + c] = tl[rr][c];
    }
}

// ---------------- GEMM: C[M][N] = A[M][K] * BT[N][K]^T (+bias), fp16 in ----------------
// 128x128 tile, BK=64 staged as two 32-half planes (dense, conflict-free b128 reads),
// 4 waves (2x2), 4x4 MFMA tiles/wave, global_load_lds width=16.
template <typename OutT, bool BIAS>
__global__ __launch_bounds__(256, 2)
void gemm_f16_k(const _Float16* __restrict__ A, const _Float16* __restrict__ BT,
                OutT* __restrict__ C, const float* __restrict__ bias,
                int M, int N, int K) {
    __shared__ _Float16 As[2][128][32];
    __shared__ _Float16 Bs[2][128][32];
    const int tid = threadIdx.x;
    const int wid = tid >> 6, lane = tid & 63;
    const int qd = lane >> 4, ln = lane & 15;
    const int m0 = blockIdx.x * 128, n0 = blockIdx.y * 128;
    const int wm = (wid >> 1) * 64, wn = (wid & 1) * 64;

    f32x4_t acc[4][4] = {};

    const int srow = lane >> 2;        // 0..15 within a 16-row segment
    const int skk  = (lane & 3) * 8;   // k offset in halfs within a plane

    for (int k0 = 0; k0 < K; k0 += 64) {
        __syncthreads();
#pragma unroll
        for (int p = 0; p < 4; ++p) {
            const int seg = p * 4 + wid;           // 0..15
            const int s   = seg >> 3;              // plane
            const int rg  = seg & 7;               // row group
            const int row = rg * 16 + srow;        // 0..127
            const size_t goff = (size_t)row * K + k0 + s * 32 + skk;
            async_copy16(&As[0][0][0] + seg * 512, A  + (size_t)m0 * K + goff);
            async_copy16(&Bs[0][0][0] + seg * 512, BT + (size_t)n0 * K + goff);
        }
        __syncthreads();
#pragma unroll
        for (int s = 0; s < 2; ++s) {
            f16x8_t a[4], b[4];
#pragma unroll
            for (int i = 0; i < 4; ++i)
                a[i] = *(const f16x8_t*)&As[s][wm + i * 16 + ln][qd * 8];
#pragma unroll
            for (int j = 0; j < 4; ++j)
                b[j] = *(const f16x8_t*)&Bs[s][wn + j * 16 + ln][qd * 8];
#pragma unroll
            for (int i = 0; i < 4; ++i)
#pragma unroll
                for (int j = 0; j < 4; ++j)
                    acc[i][j] = MFMA32(a[i], b[j], acc[i][j]);
        }
    }
#pragma unroll
    for (int i = 0; i < 4; ++i)
#pragma unroll
        for (int j = 0; j < 4; ++j) {
            const int col = n0 + wn + j * 16 + ln;
            const float bv = BIAS ? bias[col] : 0.0f;
#pragma unroll
            for (int r = 0; r < 4; ++r) {
                const int row = m0 + wm + i * 16 + qd * 4 + r;
                C[(size_t)row * N + col] = (OutT)(acc[i][j][r] + bv);
            }
        }
}

// ---------------- per-head LayerNorm on q,k; cast v; repack to [b,h,n,d] fp16 ----------------
// Q gets * sqrt(64) * log2(e) folded in so attention can use exp2.
__global__ void ln_qkv_k(const _Float16* __restrict__ qkv, const float* __restrict__ ln_w,
                         const float* __restrict__ ln_b, _Float16* __restrict__ Qb,
                         _Float16* __restrict__ Kb, _Float16* __restrict__ Vb) {
    const int tid = threadIdx.x;
    const int wid = tid >> 6, lane = tid & 63;
    const int row = blockIdx.x * 4 + wid;   // 0..65535 = (token, head)
    const int t = row >> 4;                 // token 0..4095
    const int h = row & 15;
    const int b = t >> 11, n = t & 2047;
    const size_t base = (size_t)t * 3072 + h * 64 + lane;
    float q = (float)qkv[base];
    float k = (float)qkv[base + 1024];
    float v = (float)qkv[base + 2048];
    const float wv = ln_w[lane], bv = ln_b[lane];

    float sq = q, sk = k;
#pragma unroll
    for (int m = 1; m < 64; m <<= 1) { sq += __shfl_xor(sq, m); sk += __shfl_xor(sk, m); }
    sq *= (1.0f / 64.0f); sk *= (1.0f / 64.0f);
    const float dq = q - sq, dk = k - sk;
    float vq = dq * dq, vk = dk * dk;
#pragma unroll
    for (int m = 1; m < 64; m <<= 1) { vq += __shfl_xor(vq, m); vk += __shfl_xor(vk, m); }
    vq *= (1.0f / 64.0f); vk *= (1.0f / 64.0f);
    const float yq = dq * rsqrtf(vq + 1e-5f) * wv + bv;
    const float yk = dk * rsqrtf(vk + 1e-5f) * wv + bv;
    const size_t obase = ((size_t)((b * 16 + h) * 2048 + n)) * 64 + lane;
    Qb[obase] = (_Float16)(yq * (8.0f * LOG2E));
    Kb[obase] = (_Float16)yk;
    Vb[obase] = (_Float16)v;
}

// ---------------- flash-style causal attention, S^T formulation ----------------
// grid: (B*H, 16 band-pairs). Block = 4 waves; wave w owns q rows [band*64+w*16,+16)
// of BOTH paired bands (lo=pair, hi=31-pair) -> every block does exactly 33
// band-set-steps (perfect balance; staged K/V reused by 128 q rows).
// S^T = K·Q^T via mfma 16x16x32: C-layout puts q=ln in-lane -> row max/sum are
// in-register + 2 shuffles. P^T's C-layout == B-operand layout of 16x16x16 MFMA,
// so O^T += V^T·P^T consumes P straight from registers (no LDS round-trip).
// V^T in LDS with XOR-swizzled 8B chunks (row 128B): conflict-free b64 reads.
__global__ __launch_bounds__(256, 2)
void attn_k(const _Float16* __restrict__ Q, const _Float16* __restrict__ K,
            const _Float16* __restrict__ V, _Float16* __restrict__ O) {
    __shared__ _Float16 Ks[2][64][32];
    __shared__ _Float16 VT[64][64];

    const int tid = threadIdx.x;
    const int wid = tid >> 6, lane = tid & 63;
    const int qd = lane >> 4, ln = lane & 15;
    const int bh = blockIdx.x;
    const int b = bh >> 4, h = bh & 15;
    const int lob = blockIdx.y;            // 0..15
    const int hib = 31 - lob;              // 16..31
    const size_t kvbase = (size_t)bh * 2048 * 64;
    const int qh0 = hib * 64 + wid * 16;
    const int ql0 = lob * 64 + wid * 16;

    // Q fragments (serve as the MFMA B operand; q=ln, k spread) for both bands.
    f16x8_t qfh[2], qfl[2];
#pragma unroll
    for (int s = 0; s < 2; ++s) {
        qfh[s] = *(const f16x8_t*)&Q[kvbase + (size_t)(qh0 + ln) * 64 + s * 32 + qd * 8];
        qfl[s] = *(const f16x8_t*)&Q[kvbase + (size_t)(ql0 + ln) * 64 + s * 32 + qd * 8];
    }

    f32x4_t oh[4] = {}, olo[4] = {};       // O^T acc: lane ln=q, d=dt*16+qd*4+r
    float mh = -3.0e38f, ml = -3.0e38f;    // running max (log2 domain), per q=ln
    float lh = 0.0f, ll = 0.0f;            // per-lane PARTIAL row sums (qd quarter)

    const int nst = hib + 1;

    for (int st = 0; st < nst; ++st) {
        const int kv0 = st * 64;
        __syncthreads();
        // stage K (async, 2 passes/wave) into split planes
#pragma unroll
        for (int p = 0; p < 2; ++p) {
            const int seg = p * 4 + wid;        // 0..7
            const int oh_ = seg * 512;          // uniform half index of segment base
            const int hidx = oh_ + lane * 8;    // this lane's half index
            const int s_ = hidx >> 11;
            const int rrow = (hidx >> 5) & 63;
            const int kk = hidx & 31;
            async_copy16((_Float16*)Ks + oh_,
                         K + kvbase + (size_t)(kv0 + rrow) * 64 + s_ * 32 + kk);
        }
        // stage V transposed with XOR-swizzled 8B chunks (conflict-free writes+reads)
#pragma unroll
        for (int e = 0; e < 2; ++e) {
            const int idx = tid + e * 256;      // 0..511
            const int kv = idx & 63;
            const int d0 = (idx >> 6) * 8;      // 0..56
            f16x8_t vv = *(const f16x8_t*)&V[kvbase + (size_t)(kv0 + kv) * 64 + d0];
#pragma unroll
            for (int j = 0; j < 8; ++j) {
                const int d = d0 + j;
                const int col = (((kv >> 2) ^ (d & 15)) << 2) | (kv & 3);
                VT[d][col] = vv[j];
            }
        }
        __syncthreads();

        // shared fragments for this KV tile
        f16x8_t kb[4][2];                   // A operand of S^T: kv=jt*16+ln rows
#pragma unroll
        for (int jt = 0; jt < 4; ++jt)
#pragma unroll
            for (int s = 0; s < 2; ++s)
                kb[jt][s] = *(const f16x8_t*)&Ks[s][jt * 16 + ln][qd * 8];
        f16x4_t vf[4][4];                   // A operand of PV: V^T[d=dt*16+ln][kv chunk]
#pragma unroll
        for (int dt = 0; dt < 4; ++dt)
#pragma unroll
            for (int c = 0; c < 4; ++c)
                vf[dt][c] = *(const f16x4_t*)&VT[dt * 16 + ln][(((c * 4 + qd) ^ ln) << 2)];

        auto process = [&](const f16x8_t (&qf)[2], f32x4_t (&o)[4], float& m, float& l,
                           int q0w, bool diag) {
            // S^T tiles: D[kv=qd*4+r (+16jt)][q=ln]
            f32x4_t sc[4];
#pragma unroll
            for (int jt = 0; jt < 4; ++jt) {
                f32x4_t s = {};
                s = MFMA32(kb[jt][0], qf[0], s);
                s = MFMA32(kb[jt][1], qf[1], s);
                sc[jt] = s;
            }
            if (diag) {
                const int qq = q0w + ln;
#pragma unroll
                for (int c = 0; c < 4; ++c)
#pragma unroll
                    for (int r = 0; r < 4; ++r)
                        if (kv0 + c * 16 + qd * 4 + r > qq) sc[c][r] = -3.0e38f;
            }
            // in-register max over this lane's 16 kv, then cross-quarter (2 shfl)
            float mx = sc[0][0];
#pragma unroll
            for (int c = 0; c < 4; ++c)
#pragma unroll
                for (int r = 0; r < 4; ++r) mx = fmaxf(mx, sc[c][r]);
            mx = fmaxf(mx, __shfl_xor(mx, 16));
            mx = fmaxf(mx, __shfl_xor(mx, 32));
            const float mn = fmaxf(m, mx);
            const float al = exp2f(m - mn);
            m = mn;
            float rs = 0.0f;
            f16x4_t pf[4];
#pragma unroll
            for (int c = 0; c < 4; ++c)
#pragma unroll
                for (int r = 0; r < 4; ++r) {
                    const float p = exp2f(sc[c][r] - mn);
                    rs += p;
                    pf[c][r] = (_Float16)p;
                }
            l = l * al + rs;
#pragma unroll
            for (int dt = 0; dt < 4; ++dt) o[dt] *= al;
#pragma unroll
            for (int dt = 0; dt < 4; ++dt)
#pragma unroll
                for (int c = 0; c < 4; ++c)
                    o[dt] = MFMA16(vf[dt][c], pf[c], o[dt]);
        };

        process(qfh, oh, mh, lh, qh0, st == hib);
        if (st <= lob) process(qfl, olo, ml, ll, ql0, st == lob);
    }

    // epilogue: finish row sums across quarters, normalize, store f16x4
    auto epi = [&](f32x4_t (&o)[4], float l, int q0w) {
        float t = l + __shfl_xor(l, 16);
        t = t + __shfl_xor(t, 32);
        const float inv = 1.0f / t;
        const size_t base = ((size_t)(b * 2048 + q0w + ln)) * 1024 + h * 64 + qd * 4;
#pragma unroll
        for (int dt = 0; dt < 4; ++dt) {
            f16x4_t ov;
#pragma unroll
            for (int r = 0; r < 4; ++r) ov[r] = (_Float16)(o[dt][r] * inv);
            *(f16x4_t*)&O[base + dt * 16] = ov;
        }
    };
    epi(oh, lh, qh0);
    epi(olo, ll, ql0);
}

extern "C" void kernel_launch(void* const* d_in, const int* in_sizes, int n_in,
                              void* d_out, int out_size, void* d_ws, size_t ws_size,
                              hipStream_t stream) {
    const float* x      = (const float*)d_in[0];
    const float* w_qkv  = (const float*)d_in[1];
    const float* w_proj = (const float*)d_in[2];
    const float* b_proj = (const float*)d_in[3];
    const float* ln_w   = (const float*)d_in[4];
    const float* ln_b   = (const float*)d_in[5];
    float* out = (float*)d_out;

    // workspace partition
    char* w = (char*)d_ws;
    _Float16*  qkv    = (_Float16*)w;  w += (size_t)4096 * 3072 * 2;  // 24 MB
    _Float16*  xh     = (_Float16*)w;  w += (size_t)4096 * 1024 * 2;  // 8 MB
    _Float16*  wqkvT  = (_Float16*)w;  w += (size_t)3072 * 1024 * 2;  // 6 MB
    _Float16*  wprojT = (_Float16*)w;  w += (size_t)1024 * 1024 * 2;  // 2 MB
    _Float16*  Qb     = (_Float16*)w;  w += (size_t)32 * 2048 * 64 * 2; // 8 MB
    _Float16*  Kb     = (_Float16*)w;  w += (size_t)32 * 2048 * 64 * 2; // 8 MB
    _Float16*  Vb     = (_Float16*)w;  w += (size_t)32 * 2048 * 64 * 2; // 8 MB
    _Float16*  Ah     = (_Float16*)w;  w += (size_t)4096 * 1024 * 2;  // 8 MB

    cast_f32_f16_k<<<4096, 256, 0, stream>>>(x, xh, 4096 * 1024 / 4);
    transpose_cast_k<<<dim3(48, 16), 256, 0, stream>>>(w_qkv, wqkvT, 1024, 3072);
    transpose_cast_k<<<dim3(16, 16), 256, 0, stream>>>(w_proj, wprojT, 1024, 1024);
    gemm_f16_k<_Float16, false><<<dim3(32, 24), 256, 0, stream>>>(xh, wqkvT, qkv, nullptr, 4096, 3072, 1024);
    ln_qkv_k<<<16384, 256, 0, stream>>>(qkv, ln_w, ln_b, Qb, Kb, Vb);
    attn_k<<<dim3(32, 16), 256, 0, stream>>>(Qb, Kb, Vb, Ah);
    gemm_f16_k<float, true><<<dim3(32, 8), 256, 0, stream>>>(Ah, wprojT, out, b_proj, 4096, 1024, 1024);
}